// Round 1
// 1328.093 us; speedup vs baseline: 1.0749x; 1.0749x over previous
//
#include <hip/hip_runtime.h>

namespace {

constexpr int NP   = 19712;   // padded tokens (Nystrom)
constexpr int NT   = 19601;   // tokens incl cls
constexpr int NPIX = 19600;   // feature tokens (140x140)
constexpr int HD   = 512;     // hidden dim
constexpr int ID   = 1024;    // input dim
constexpr int NH   = 8;       // heads
constexpr int DH   = 8;       // dim per head
constexpr int NL   = 256;     // landmarks
constexpr int PADR = 111;     // left zero-pad rows
constexpr int SIDE = 140;
constexpr int CCH  = 128;     // ppeg channel chunk
constexpr int PW   = 148;     // padded image row stride (floats)
constexpr int CKT  = NP / 4;  // attn3v token chunk = 4928

typedef __attribute__((ext_vector_type(8))) short bf16x8;
typedef __attribute__((ext_vector_type(4))) float f32x4;

#define F4MAD(a, s, v) { (a).x += (s)*(v).x; (a).y += (s)*(v).y; (a).z += (s)*(v).z; (a).w += (s)*(v).w; }

// async global->LDS, 16B per lane; LDS dest must be wave-uniform-base + lane*16
#define GLOAD16(gptr, lptr) \
    __builtin_amdgcn_global_load_lds((const __attribute__((address_space(1))) void*)(gptr), \
                                     (__attribute__((address_space(3))) void*)(lptr), 16, 0, 0)

__device__ inline short f2bf(float f) {
    union { float f; unsigned u; } v; v.f = f;
    unsigned r = v.u + 0x7fffu + ((v.u >> 16) & 1u);
    return (short)(r >> 16);
}

// ------------------------------------------------------------------
// cast X fp32 -> bf16 elementwise
// ------------------------------------------------------------------
__global__ void castX(const float* __restrict__ src, short* __restrict__ dst)
{
    size_t c = (size_t)blockIdx.x * 256 + threadIdx.x;
    const float4 x0 = *(const float4*)&src[c * 8];
    const float4 x1 = *(const float4*)&src[c * 8 + 4];
    bf16x8 p;
    p[0] = f2bf(x0.x); p[1] = f2bf(x0.y); p[2] = f2bf(x0.z); p[3] = f2bf(x0.w);
    p[4] = f2bf(x1.x); p[5] = f2bf(x1.y); p[6] = f2bf(x1.z); p[7] = f2bf(x1.w);
    *(bf16x8*)&dst[c * 8] = p;
}

// ------------------------------------------------------------------
// cast+transpose: dst[c][r] = bf16(src[r][c]); grid (C/32, R/32)
// ------------------------------------------------------------------
__global__ void castT(const float* __restrict__ src, short* __restrict__ dst, int R, int C)
{
    __shared__ float t[32][33];
    const int tx = threadIdx.x & 31, ty = threadIdx.x >> 5;
    const int c0 = blockIdx.x * 32, r0 = blockIdx.y * 32;
    #pragma unroll
    for (int j = 0; j < 4; ++j)
        t[ty + 8 * j][tx] = src[(size_t)(r0 + ty + 8 * j) * C + c0 + tx];
    __syncthreads();
    #pragma unroll
    for (int j = 0; j < 4; ++j)
        dst[(size_t)(c0 + ty + 8 * j) * R + r0 + tx] = f2bf(t[tx][ty + 8 * j]);
}

// ------------------------------------------------------------------
// fc1 MFMA: out[1+m][n] = gelu(Xb[m] @ W[:,n] + b[n])
// m97-style: 128x128 tile, BK=64, global_load_lds + chunk XOR swizzle.
// Rows >= NPIX read garbage (xb allocated to NP rows) and are discarded
// at the C-write -- MFMA rows are independent, so no contamination.
// grid (154, 4), 256 threads (4 waves, 2x2, each 64x64 out)
// ------------------------------------------------------------------
__global__ __launch_bounds__(256) void gemm_fc1(const short* __restrict__ Xb,
                                                const short* __restrict__ Wt,
                                                const float* __restrict__ bias,
                                                float* __restrict__ out)
{
    __shared__ __align__(16) short As[128 * 64];
    __shared__ __align__(16) short Bs[128 * 64];
    const int tid  = threadIdx.x;
    const int row0 = blockIdx.x * 128;
    const int col0 = blockIdx.y * 128;
    const int wave = tid >> 6, lane = tid & 63;
    const int quad = lane >> 4, l16 = lane & 15;
    const int m_base = (wave >> 1) * 64, n_base = (wave & 1) * 64;
    f32x4 acc[4][4] = {};

    // staging map: slot = i*256 + wave*64 + lane; LDS dest linear (slot*16B);
    // global source pre-swizzled: chunk qd = (slot&7) ^ (row&7)
    int    ldsoff[4];
    size_t agoff[4], bgoff[4];
    #pragma unroll
    for (int i = 0; i < 4; ++i) {
        int slot = i * 256 + wave * 64 + lane;
        int row  = slot >> 3;
        int qd   = (slot & 7) ^ (row & 7);
        ldsoff[i] = slot * 8;
        agoff[i] = (size_t)(row0 + row) * ID + qd * 8;
        bgoff[i] = (size_t)(col0 + row) * ID + qd * 8;
    }

    for (int k0 = 0; k0 < ID; k0 += 64) {
        #pragma unroll
        for (int i = 0; i < 4; ++i) GLOAD16(&Xb[agoff[i] + k0], &As[ldsoff[i]]);
        #pragma unroll
        for (int i = 0; i < 4; ++i) GLOAD16(&Wt[bgoff[i] + k0], &Bs[ldsoff[i]]);
        __syncthreads();
        #pragma unroll
        for (int kk = 0; kk < 2; ++kk) {
            bf16x8 af[4], bfr[4];
            #pragma unroll
            for (int i = 0; i < 4; ++i) {
                int ar = m_base + i * 16 + l16;
                af[i]  = *(const bf16x8*)&As[(ar * 8 + ((kk * 4 + quad) ^ (ar & 7))) * 8];
                int br = n_base + i * 16 + l16;
                bfr[i] = *(const bf16x8*)&Bs[(br * 8 + ((kk * 4 + quad) ^ (br & 7))) * 8];
            }
            #pragma unroll
            for (int mi = 0; mi < 4; ++mi)
                #pragma unroll
                for (int ni = 0; ni < 4; ++ni)
                    acc[mi][ni] = __builtin_amdgcn_mfma_f32_16x16x32_bf16(af[mi], bfr[ni], acc[mi][ni], 0, 0, 0);
        }
        __syncthreads();
    }
    #pragma unroll
    for (int mi = 0; mi < 4; ++mi) {
        #pragma unroll
        for (int r = 0; r < 4; ++r) {
            int gr = row0 + m_base + mi * 16 + quad * 4 + r;
            if (gr >= NPIX) continue;
            #pragma unroll
            for (int ni = 0; ni < 4; ++ni) {
                int gc = col0 + n_base + ni * 16 + l16;
                float v = acc[mi][ni][r] + bias[gc];
                v = 0.5f * v * (1.f + erff(v * 0.70710678118654752f));
                out[(size_t)(gr + 1) * HD + gc] = v;
            }
        }
    }
}

// ------------------------------------------------------------------
// qkv MFMA: 64x64 tile. grid (308, 3)
// ------------------------------------------------------------------
__global__ __launch_bounds__(256) void gemm_qkv(const short* __restrict__ xpB,
                                                const short* __restrict__ Wt,
                                                float* __restrict__ qh,
                                                float* __restrict__ kh,
                                                float* __restrict__ vh)
{
    __shared__ __align__(16) short As[64 * 40];
    __shared__ __align__(16) short Bs[64 * 40];
    const int tid  = threadIdx.x;
    const int row0 = blockIdx.x * 64;
    const int col0 = blockIdx.y * 64;
    const int wave = tid >> 6, lane = tid & 63;
    const int quad = lane >> 4, l16 = lane & 15;
    const int m_off = (wave >> 1) * 32, n_off = (wave & 1) * 32;
    f32x4 acc[2][2] = {};
    for (int k0 = 0; k0 < HD; k0 += 32) {
        {
            int row = tid >> 2, kc = (tid & 3) * 8;
            *(bf16x8*)&As[row * 40 + kc] =
                *(const bf16x8*)&xpB[(size_t)(row0 + row) * HD + k0 + kc];
            *(bf16x8*)&Bs[row * 40 + kc] =
                *(const bf16x8*)&Wt[(size_t)(col0 + row) * HD + k0 + kc];
        }
        __syncthreads();
        bf16x8 af[2], bf[2];
        #pragma unroll
        for (int i = 0; i < 2; ++i) {
            af[i] = *(const bf16x8*)&As[(m_off + i * 16 + l16) * 40 + quad * 8];
            bf[i] = *(const bf16x8*)&Bs[(n_off + i * 16 + l16) * 40 + quad * 8];
        }
        #pragma unroll
        for (int mi = 0; mi < 2; ++mi)
            #pragma unroll
            for (int ni = 0; ni < 2; ++ni)
                acc[mi][ni] = __builtin_amdgcn_mfma_f32_16x16x32_bf16(af[mi], bf[ni], acc[mi][ni], 0, 0, 0);
        __syncthreads();
    }
    const int which = blockIdx.y;
    float* dst = (which == 0) ? qh : (which == 1) ? kh : vh;
    const float scale = (which == 0) ? 0.35355339059327373f : 1.f;
    #pragma unroll
    for (int mi = 0; mi < 2; ++mi) {
        #pragma unroll
        for (int r = 0; r < 4; ++r) {
            int gr = row0 + m_off + mi * 16 + quad * 4 + r;
            #pragma unroll
            for (int ni = 0; ni < 2; ++ni) {
                int n = n_off + ni * 16 + l16;
                int hh = n >> 3, d = n & 7;
                dst[((size_t)hh * NP + gr) * DH + d] = acc[mi][ni][r] * scale;
            }
        }
    }
}

__global__ void cls_init(const float* __restrict__ cls, float* __restrict__ h)
{
    int t = blockIdx.x * 256 + threadIdx.x;
    if (t < HD) h[t] = cls[t];
}

__global__ void copy512(const float* __restrict__ src, float* __restrict__ dst)
{
    dst[threadIdx.x] = src[threadIdx.x];
}

// ------------------------------------------------------------------
// layernorm rows of h into xp (bf16), first 111 rows zero
// ------------------------------------------------------------------
__global__ void ln_pad(const float* __restrict__ h, const float* __restrict__ g,
                       const float* __restrict__ b, short* __restrict__ xp)
{
    const int row = blockIdx.x;
    const int tid = threadIdx.x;
    short* dst = xp + (size_t)row * HD;
    if (row < PADR) { dst[tid] = 0; dst[tid + 256] = 0; return; }
    const float* src = h + (size_t)(row - PADR) * HD;
    float v0 = src[tid], v1 = src[tid + 256];
    __shared__ float red[256];
    red[tid] = v0 + v1;
    __syncthreads();
    for (int off = 128; off > 0; off >>= 1) {
        if (tid < off) red[tid] += red[tid + off];
        __syncthreads();
    }
    float mu = red[0] * (1.f / HD);
    __syncthreads();
    float d0 = v0 - mu, d1 = v1 - mu;
    red[tid] = d0 * d0 + d1 * d1;
    __syncthreads();
    for (int off = 128; off > 0; off >>= 1) {
        if (tid < off) red[tid] += red[tid + off];
        __syncthreads();
    }
    float inv = rsqrtf(red[0] * (1.f / HD) + 1e-5f);
    dst[tid]       = f2bf(d0 * inv * g[tid] + b[tid]);
    dst[tid + 256] = f2bf(d1 * inv * g[tid + 256] + b[tid + 256]);
}

// ------------------------------------------------------------------
// landmark means
// ------------------------------------------------------------------
__global__ void landmarks(const float* __restrict__ qh, const float* __restrict__ kh,
                          float* __restrict__ ql, float* __restrict__ kl)
{
    int idx = blockIdx.x * 256 + threadIdx.x;
    int sel = idx >> 14;
    int rem = idx & 16383;
    int h = rem >> 11;
    int i = (rem >> 3) & 255;
    int d = rem & 7;
    const float* src = sel ? kh : qh;
    size_t base = ((size_t)h * NP + (size_t)i * 77) * DH + d;
    float s = 0.f;
    for (int j = 0; j < 77; ++j) s += src[base + (size_t)j * DH];
    (sel ? kl : ql)[((size_t)h * NL + i) * DH + d] = s * (1.f / 77.f);
}

// ------------------------------------------------------------------
// attn2 = softmax(q_l @ k_l^T); scores are O(1) -> no max subtraction
// ------------------------------------------------------------------
__global__ void attn2_softmax(const float* __restrict__ ql, const float* __restrict__ kl,
                              float* __restrict__ a)
{
    const int i = blockIdx.x, h = blockIdx.y, j = threadIdx.x;
    __shared__ float sq[8];
    __shared__ float red[256];
    if (j < 8) sq[j] = ql[((size_t)h * NL + i) * DH + j];
    __syncthreads();
    const float* kr = kl + ((size_t)h * NL + j) * DH;
    float s = 0.f;
    #pragma unroll
    for (int d = 0; d < 8; ++d) s += sq[d] * kr[d];
    float e = __expf(s);
    red[j] = e;
    __syncthreads();
    for (int off = 128; off > 0; off >>= 1) {
        if (j < off) red[j] += red[j + off];
        __syncthreads();
    }
    a[((size_t)h * NL + i) * NL + j] = e / red[0];
}

// ------------------------------------------------------------------
// pinv init
// ------------------------------------------------------------------
__global__ void pinv_norms(const float* __restrict__ a, float* __restrict__ part)
{
    const int h = blockIdx.x & 7;
    const int mode = blockIdx.x >> 3;
    const int tid = threadIdx.x;
    const float* ah = a + (size_t)h * NL * NL;
    float s = 0.f;
    if (mode == 0) { for (int j = 0; j < NL; ++j) s += fabsf(ah[tid * NL + j]); }
    else           { for (int i = 0; i < NL; ++i) s += fabsf(ah[i * NL + tid]); }
    __shared__ float red[256];
    red[tid] = s;
    __syncthreads();
    for (int off = 128; off > 0; off >>= 1) {
        if (tid < off) red[tid] = fmaxf(red[tid], red[tid + off]);
        __syncthreads();
    }
    if (tid == 0) part[mode * 8 + h] = red[0];
}

__global__ void z0_init(const float* __restrict__ a, const float* __restrict__ part,
                        float* __restrict__ z)
{
    float s1 = part[0], s2 = part[8];
    #pragma unroll
    for (int h = 1; h < 8; ++h) { s1 = fmaxf(s1, part[h]); s2 = fmaxf(s2, part[8 + h]); }
    float inv = 1.f / (s1 * s2);
    int idx = blockIdx.x * 256 + threadIdx.x;
    int h = idx >> 16;
    int rem = idx & 65535;
    int i = rem >> 8, j = rem & 255;
    z[idx] = a[((size_t)h * NL + j) * NL + i] * inv;
}

// ------------------------------------------------------------------
// batched 256x256x256 generalized:
//   D = alpha*(A@B) + cA*A + cB*B + cI*I   grid (8,4,8)
// ------------------------------------------------------------------
__global__ void mm256g(const float* __restrict__ A, const float* __restrict__ B,
                       float* __restrict__ D, float alpha, float cA, float cB, float cI)
{
    const int h = blockIdx.z;
    const float* Ah = A + (size_t)h * NL * NL;
    const float* Bh = B + (size_t)h * NL * NL;
    float* Dh = D + (size_t)h * NL * NL;
    __shared__ __align__(16) float As[16][36];
    __shared__ __align__(16) float Bs[16][68];
    const int tid = threadIdx.x;
    const int tx = tid & 15, ty = tid >> 4;
    const int row0 = blockIdx.x * 32;
    const int col0 = blockIdx.y * 64;
    float acc[2][4] = {};
    const int ar = tid >> 3;
    const int ak = (tid & 7) * 2;
    const int bk = tid >> 4;
    const int bj = (tid & 15) * 4;
    for (int k0 = 0; k0 < NL; k0 += 16) {
        float2 av = *(const float2*)&Ah[(size_t)(row0 + ar) * NL + k0 + ak];
        As[ak][ar] = av.x; As[ak + 1][ar] = av.y;
        *(float4*)&Bs[bk][bj] = *(const float4*)&Bh[(size_t)(k0 + bk) * NL + col0 + bj];
        __syncthreads();
        #pragma unroll
        for (int k = 0; k < 16; ++k) {
            float2 a = *(const float2*)&As[k][ty * 2];
            float4 b = *(const float4*)&Bs[k][tx * 4];
            acc[0][0] += a.x * b.x; acc[0][1] += a.x * b.y; acc[0][2] += a.x * b.z; acc[0][3] += a.x * b.w;
            acc[1][0] += a.y * b.x; acc[1][1] += a.y * b.y; acc[1][2] += a.y * b.z; acc[1][3] += a.y * b.w;
        }
        __syncthreads();
    }
    #pragma unroll
    for (int r = 0; r < 2; ++r) {
        int gr = row0 + ty * 2 + r;
        #pragma unroll
        for (int c = 0; c < 4; ++c) {
            int gc = col0 + tx * 4 + c;
            float v = alpha * acc[r][c]
                    + cA * Ah[(size_t)gr * NL + gc]
                    + cB * Bh[(size_t)gr * NL + gc];
            if (gr == gc) v += cI;
            Dh[(size_t)gr * NL + gc] = v;
        }
    }
}

// ------------------------------------------------------------------
// vout[h] = scale * M[h] @ vin[h];  M: [8][256][256], v: [8][256][8]
// grid (8 rowchunks, 8 heads), 256 threads
// ------------------------------------------------------------------
__global__ void polyv(const float* __restrict__ M, const float* __restrict__ vin,
                      float* __restrict__ vout, float scale)
{
    const int h = blockIdx.y;
    __shared__ float vs[NL * DH];
    const int tid = threadIdx.x;
    const float* vh = vin + (size_t)h * NL * DH;
    #pragma unroll
    for (int i = 0; i < 8; ++i) vs[tid + 256 * i] = vh[tid + 256 * i];
    __syncthreads();
    const int row = blockIdx.x * 32 + (tid >> 3);
    const int d = tid & 7;
    const float* Mr = M + ((size_t)h * NL + row) * NL;
    float acc = 0.f;
    #pragma unroll 4
    for (int j = 0; j < NL; j += 4) {
        float4 m = *(const float4*)&Mr[j];
        acc += m.x * vs[j * 8 + d]      + m.y * vs[j * 8 + 8 + d]
             + m.z * vs[j * 8 + 16 + d] + m.w * vs[j * 8 + 24 + d];
    }
    vout[((size_t)h * NL + row) * DH + d] = acc * scale;
}

// ------------------------------------------------------------------
// attn3 @ v: no-max softmax (scores O(1)); 4 landmarks/block, 4 chunks
// ------------------------------------------------------------------
__global__ void attn3v(const float* __restrict__ kh, const float* __restrict__ vh,
                       const float* __restrict__ ql, float* __restrict__ part)
{
    const int i0 = blockIdx.x * 4, h = blockIdx.y, ck = blockIdx.z, tid = threadIdx.x;
    __shared__ float sq[4][8];
    __shared__ float wred[4][4][9];
    if (tid < 32) sq[tid >> 3][tid & 7] = ql[((size_t)h * NL + i0 + (tid >> 3)) * DH + (tid & 7)];
    __syncthreads();
    float q[4][8];
    #pragma unroll
    for (int li = 0; li < 4; ++li)
        #pragma unroll
        for (int d = 0; d < 8; ++d) q[li][d] = sq[li][d];
    const float* kb = kh + (size_t)h * NP * DH;
    const float* vb = vh + (size_t)h * NP * DH;
    float den[4] = {};
    float acc[4][8] = {};
    const int tEnd = (ck + 1) * CKT;
    for (int t = ck * CKT + tid; t < tEnd; t += 256) {
        const float4 k0 = *(const float4*)&kb[(size_t)t * 8];
        const float4 k1 = *(const float4*)&kb[(size_t)t * 8 + 4];
        const float4 v0 = *(const float4*)&vb[(size_t)t * 8];
        const float4 v1 = *(const float4*)&vb[(size_t)t * 8 + 4];
        float vv[8] = {v0.x, v0.y, v0.z, v0.w, v1.x, v1.y, v1.z, v1.w};
        float kk[8] = {k0.x, k0.y, k0.z, k0.w, k1.x, k1.y, k1.z, k1.w};
        #pragma unroll
        for (int li = 0; li < 4; ++li) {
            float s = 0.f;
            #pragma unroll
            for (int d = 0; d < 8; ++d) s += q[li][d] * kk[d];
            float e = __expf(s);
            den[li] += e;
            #pragma unroll
            for (int d = 0; d < 8; ++d) acc[li][d] += e * vv[d];
        }
    }
    #pragma unroll
    for (int off = 1; off < 64; off <<= 1) {
        #pragma unroll
        for (int li = 0; li < 4; ++li) {
            den[li] += __shfl_xor(den[li], off);
            #pragma unroll
            for (int d = 0; d < 8; ++d) acc[li][d] += __shfl_xor(acc[li][d], off);
        }
    }
    const int wave = tid >> 6, lane = tid & 63;
    if (lane == 0) {
        #pragma unroll
        for (int li = 0; li < 4; ++li) {
            wred[wave][li][0] = den[li];
            #pragma unroll
            for (int d = 0; d < 8; ++d) wred[wave][li][1 + d] = acc[li][d];
        }
    }
    __syncthreads();
    if (tid < 4) {
        const int li = tid;
        float D_ = 0.f;
        float A[8] = {};
        #pragma unroll
        for (int w = 0; w < 4; ++w) {
            D_ += wred[w][li][0];
            #pragma unroll
            for (int d = 0; d < 8; ++d) A[d] += wred[w][li][1 + d];
        }
        float* p = part + (((size_t)h * NL + i0 + li) * 4 + ck) * 10;
        p[0] = D_;
        #pragma unroll
        for (int d = 0; d < 8; ++d) p[1 + d] = A[d];
    }
}

// merge 4 chunks -> wbuf[h][i][d];  2048 items
__global__ void attn3v_merge(const float* __restrict__ part, float* __restrict__ wbuf)
{
    int idx = blockIdx.x * 256 + threadIdx.x;   // h*NL+i
    const float* p = part + (size_t)idx * 40;
    float D_ = 0.f;
    float A[8] = {};
    #pragma unroll
    for (int ck = 0; ck < 4; ++ck) {
        const float* q = p + ck * 10;
        D_ += q[0];
        #pragma unroll
        for (int d = 0; d < 8; ++d) A[d] += q[1 + d];
    }
    float inv = 1.f / D_;
    #pragma unroll
    for (int d = 0; d < 8; ++d) wbuf[(size_t)idx * 8 + d] = A[d] * inv;
}

// ------------------------------------------------------------------
// attn1 fused + dwconv33(v): no-max softmax; 2 lanes/token; grid (154, 8)
// ------------------------------------------------------------------
__global__ void attn1_conv(const float* __restrict__ qh, const float* __restrict__ vh,
                           const float* __restrict__ klg, const float* __restrict__ zwg,
                           const float* __restrict__ rw, float* __restrict__ aout)
{
    const int h = blockIdx.y;
    __shared__ __align__(16) float kl[NL * DH];
    __shared__ __align__(16) float zw[NL * DH];
    const int tid = threadIdx.x;
    for (int q = tid; q < NL * DH; q += 256) {
        kl[q] = klg[(size_t)h * NL * DH + q];
        zw[q] = zwg[(size_t)h * NL * DH + q];
    }
    __syncthreads();
    const int half = tid & 1;
    const int r = blockIdx.x * 128 + (tid >> 1);
    if (r >= NT) return;
    const int t = r + PADR;
    const float* qp = qh + ((size_t)h * NP + t) * DH;
    float4 q0 = *(const float4*)qp;
    float4 q1 = *(const float4*)(qp + 4);
    float den = 0.f;
    float4 acc0 = make_float4(0.f, 0.f, 0.f, 0.f);
    float4 acc1 = make_float4(0.f, 0.f, 0.f, 0.f);
    const int iBeg = half * 128, iEnd = iBeg + 128;
    for (int i = iBeg; i < iEnd; ++i) {
        float4 k0 = *(const float4*)&kl[i * 8];
        float4 k1 = *(const float4*)&kl[i * 8 + 4];
        float s = q0.x * k0.x + q0.y * k0.y + q0.z * k0.z + q0.w * k0.w
                + q1.x * k1.x + q1.y * k1.y + q1.z * k1.z + q1.w * k1.w;
        float e = __expf(s);
        den += e;
        float4 z0 = *(const float4*)&zw[i * 8];
        float4 z1 = *(const float4*)&zw[i * 8 + 4];
        F4MAD(acc0, e, z0); F4MAD(acc1, e, z1);
    }
    {
        den += __shfl_xor(den, 1);
        float a[8] = {acc0.x, acc0.y, acc0.z, acc0.w, acc1.x, acc1.y, acc1.z, acc1.w};
        #pragma unroll
        for (int d = 0; d < 8; ++d) a[d] += __shfl_xor(a[d], 1);
        float inv = 1.f / den;
        acc0 = make_float4(a[0] * inv, a[1] * inv, a[2] * inv, a[3] * inv);
        acc1 = make_float4(a[4] * inv, a[5] * inv, a[6] * inv, a[7] * inv);
    }
    const float* vb = vh + (size_t)h * NP * DH;
    float4 c0 = make_float4(0.f, 0.f, 0.f, 0.f);
    float4 c1 = make_float4(0.f, 0.f, 0.f, 0.f);
    for (int j = half; j < 33; j += 2) {
        int tp = t - 16 + j;
        if (tp >= NP) continue;
        float wv = rw[h * 33 + j];
        float4 v0 = *(const float4*)&vb[(size_t)tp * 8];
        float4 v1 = *(const float4*)&vb[(size_t)tp * 8 + 4];
        F4MAD(c0, wv, v0); F4MAD(c1, wv, v1);
    }
    c0.x += __shfl_xor(c0.x, 1); c0.y += __shfl_xor(c0.y, 1);
    c0.z += __shfl_xor(c0.z, 1); c0.w += __shfl_xor(c0.w, 1);
    c1.x += __shfl_xor(c1.x, 1); c1.y += __shfl_xor(c1.y, 1);
    c1.z += __shfl_xor(c1.z, 1); c1.w += __shfl_xor(c1.w, 1);
    if (half == 0) {
        float* op = aout + (size_t)r * 64 + h * 8;
        *(float4*)op = make_float4(acc0.x + c0.x, acc0.y + c0.y, acc0.z + c0.z, acc0.w + c0.w);
        *(float4*)(op + 4) = make_float4(acc1.x + c1.x, acc1.y + c1.y, acc1.z + c1.z, acc1.w + c1.w);
    }
}

// ------------------------------------------------------------------
// out-proj + residual: 16 rows/block
// ------------------------------------------------------------------
__global__ void outproj(const float* __restrict__ aout, const float* __restrict__ W,
                        const float* __restrict__ bias, float* __restrict__ h)
{
    const int r0 = blockIdx.x * 16;
    const int tid = threadIdx.x;   // 512
    __shared__ float ao[16][64];
    #pragma unroll
    for (int s = 0; s < 2; ++s) {
        int idx = tid + s * 512;
        int rr = idx >> 6, kk = idx & 63;
        int gr = r0 + rr;
        ao[rr][kk] = (gr < NT) ? aout[(size_t)gr * 64 + kk] : 0.f;
    }
    __syncthreads();
    float acc[16] = {};
    for (int k = 0; k < 64; ++k) {
        float wv = W[(size_t)k * HD + tid];
        #pragma unroll
        for (int r = 0; r < 16; ++r) acc[r] += ao[r][k] * wv;
    }
    float bv = bias[tid];
    #pragma unroll
    for (int r = 0; r < 16; ++r) {
        int gr = r0 + r;
        if (gr < NT) h[(size_t)gr * HD + tid] += acc[r] + bv;
    }
}

// ------------------------------------------------------------------
// PPEG
// ------------------------------------------------------------------
__global__ void ppeg_wprep(const float* __restrict__ w7, const float* __restrict__ b7,
                           const float* __restrict__ w5, const float* __restrict__ b5,
                           const float* __restrict__ w3, const float* __restrict__ b3,
                           float* __restrict__ wc, float* __restrict__ bsum)
{
    int idx = blockIdx.x * 256 + threadIdx.x;
    if (idx < HD * 49) {
        int c = idx / 49, t = idx - c * 49;
        int dy = t / 7 - 3, dx = t % 7 - 3;
        float v = w7[idx];
        if (dy >= -2 && dy <= 2 && dx >= -2 && dx <= 2) v += w5[c * 25 + (dy + 2) * 5 + (dx + 2)];
        if (dy >= -1 && dy <= 1 && dx >= -1 && dx <= 1) v += w3[c * 9 + (dy + 1) * 3 + (dx + 1)];
        if (t == 24) v += 1.f;
        wc[idx] = v;
    } else if (idx < HD * 49 + HD) {
        int c = idx - HD * 49;
        bsum[c] = b7[c] + b5[c] + b3[c];
    }
}

__global__ void ppeg_t1(const float* __restrict__ hin, float* __restrict__ plan, int ch0)
{
    __shared__ float tile[32][33];
    const int tx = threadIdx.x & 31, ty = threadIdx.x >> 5;
    const int p0 = blockIdx.x * 32;
    const int c0 = ch0 + blockIdx.y * 32;
    #pragma unroll
    for (int j = 0; j < 4; ++j) {
        int p = p0 + ty + j * 8;
        tile[ty + j * 8][tx] = (p < NPIX) ? hin[(size_t)(1 + p) * HD + c0 + tx] : 0.f;
    }
    __syncthreads();
    #pragma unroll
    for (int j = 0; j < 4; ++j) {
        int p = p0 + tx;
        int cc = ty + j * 8;
        if (p < NPIX) plan[(size_t)(blockIdx.y * 32 + cc) * NPIX + p] = tile[tx][cc];
    }
}

__global__ __launch_bounds__(256) void ppeg_conv(const float* __restrict__ plan,
                                                 const float* __restrict__ wc,
                                                 float* __restrict__ plan2, int ch0)
{
    __shared__ __align__(16) float img[41 * PW];
    const int tid = threadIdx.x;
    const int cl = blockIdx.x;
    const int yq = blockIdx.y;
    for (int i = tid; i < 41 * PW; i += 256) img[i] = 0.f;
    __syncthreads();
    const float* src = plan + (size_t)cl * NPIX;
    for (int i = tid; i < 41 * SIDE; i += 256) {
        int ly = i / SIDE, x = i - ly * SIDE;
        int y = yq * 35 - 3 + ly;
        if (y >= 0 && y < SIDE) img[ly * PW + x + 3] = src[y * SIDE + x];
    }
    const float* w = wc + (size_t)(ch0 + cl) * 49;
    float wr[49];
    #pragma unroll
    for (int t = 0; t < 49; ++t) wr[t] = w[t];
    __syncthreads();
    float* dst = plan2 + (size_t)cl * NPIX;
    for (int g = tid; g < 35 * 35; g += 256) {
        int yl = g / 35, x0 = (g - yl * 35) * 4;
        float acc0 = 0.f, acc1 = 0.f, acc2 = 0.f, acc3 = 0.f;
        #pragma unroll
        for (int a = 0; a < 7; ++a) {
            const float* row = &img[(yl + a) * PW + x0];
            float4 A = *(const float4*)(row);
            float4 B = *(const float4*)(row + 4);
            float4 C = *(const float4*)(row + 8);
            float e0 = A.x, e1 = A.y, e2 = A.z, e3 = A.w;
            float e4 = B.x, e5 = B.y, e6 = B.z, e7 = B.w;
            float e8 = C.x, e9 = C.y;
            const float w0 = wr[a*7+0], w1 = wr[a*7+1], w2 = wr[a*7+2], w3v = wr[a*7+3];
            const float w4 = wr[a*7+4], w5v = wr[a*7+5], w6 = wr[a*7+6];
            acc0 += w0*e0 + w1*e1 + w2*e2 + w3v*e3 + w4*e4 + w5v*e5 + w6*e6;
            acc1 += w0*e1 + w1*e2 + w2*e3 + w3v*e4 + w4*e5 + w5v*e6 + w6*e7;
            acc2 += w0*e2 + w1*e3 + w2*e4 + w3v*e5 + w4*e6 + w5v*e7 + w6*e8;
            acc3 += w0*e3 + w1*e4 + w2*e5 + w3v*e6 + w4*e7 + w5v*e8 + w6*e9;
        }
        *(float4*)&dst[(yq * 35 + yl) * SIDE + x0] = make_float4(acc0, acc1, acc2, acc3);
    }
}

__global__ void ppeg_t2(const float* __restrict__ plan2, const float* __restrict__ bsum,
                        float* __restrict__ hout, int ch0)
{
    __shared__ float tile[32][33];
    const int tx = threadIdx.x & 31, ty = threadIdx.x >> 5;
    const int p0 = blockIdx.x * 32;
    #pragma unroll
    for (int j = 0; j < 4; ++j) {
        int p = p0 + tx;
        int cc = ty + j * 8;
        tile[tx][cc] = (p < NPIX) ? plan2[(size_t)(blockIdx.y * 32 + cc) * NPIX + p] : 0.f;
    }
    __syncthreads();
    const int c0 = ch0 + blockIdx.y * 32;
    float bv = bsum[c0 + tx];
    #pragma unroll
    for (int j = 0; j < 4; ++j) {
        int p = p0 + ty + j * 8;
        if (p < NPIX) hout[(size_t)(1 + p) * HD + c0 + tx] = tile[ty + j * 8][tx] + bv;
    }
}

// ------------------------------------------------------------------
// final layernorm of row 0
// ------------------------------------------------------------------
__global__ void final_ln(const float* __restrict__ h, const float* __restrict__ g,
                         const float* __restrict__ b, float* __restrict__ out)
{
    const int tid = threadIdx.x;
    float v0 = h[tid], v1 = h[tid + 256];
    __shared__ float red[256];
    red[tid] = v0 + v1;
    __syncthreads();
    for (int off = 128; off > 0; off >>= 1) {
        if (tid < off) red[tid] += red[tid + off];
        __syncthreads();
    }
    float mu = red[0] * (1.f / HD);
    __syncthreads();
    float d0 = v0 - mu, d1 = v1 - mu;
    red[tid] = d0 * d0 + d1 * d1;
    __syncthreads();
    for (int off = 128; off > 0; off >>= 1) {
        if (tid < off) red[tid] += red[tid + off];
        __syncthreads();
    }
    float inv = rsqrtf(red[0] * (1.f / HD) + 1e-5f);
    out[tid]       = d0 * inv * g[tid] + b[tid];
    out[tid + 256] = d1 * inv * g[tid + 256] + b[tid + 256];
}

} // namespace

extern "C" void kernel_launch(void* const* d_in, const int* in_sizes, int n_in,
                              void* d_out, int out_size, void* d_ws, size_t ws_size,
                              hipStream_t stream)
{
    const float* x      = (const float*)d_in[0];
    const float* fc1_w  = (const float*)d_in[1];
    const float* fc1_b  = (const float*)d_in[2];
    const float* cls    = (const float*)d_in[3];
    const float* l1_g   = (const float*)d_in[4];
    const float* l1_bb  = (const float*)d_in[5];
    const float* l1_qkv = (const float*)d_in[6];
    const float* l1_ow  = (const float*)d_in[7];
    const float* l1_ob  = (const float*)d_in[8];
    const float* l1_rw  = (const float*)d_in[9];
    const float* l2_g   = (const float*)d_in[10];
    const float* l2_bb  = (const float*)d_in[11];
    const float* l2_qkv = (const float*)d_in[12];
    const float* l2_ow  = (const float*)d_in[13];
    const float* l2_ob  = (const float*)d_in[14];
    const float* l2_rw  = (const float*)d_in[15];
    const float* p7w    = (const float*)d_in[16];
    const float* p7b    = (const float*)d_in[17];
    const float* p5w    = (const float*)d_in[18];
    const float* p5b    = (const float*)d_in[19];
    const float* p3w    = (const float*)d_in[20];
    const float* p3b    = (const float*)d_in[21];
    const float* ng     = (const float*)d_in[22];
    const float* nb     = (const float*)d_in[23];
    float* out = (float*)d_out;

    char* ws = (char*)d_ws;
    size_t off = 0;
    auto alloc = [&](size_t bytes) {
        char* p = ws + off;
        off += (bytes + 255) & ~(size_t)255;
        return (void*)p;
    };
    float* bufA = (float*)alloc((size_t)NP * HD * 4);
    float* bufB = (float*)alloc((size_t)NP * HD * 4);
    float* qh   = (float*)alloc((size_t)NH * NP * DH * 4);
    float* kh   = (float*)alloc((size_t)NH * NP * DH * 4);
    float* vh   = (float*)alloc((size_t)NH * NP * DH * 4);
    float* aout = (float*)alloc((size_t)NP * 64 * 4);
    float* ql   = (float*)alloc((size_t)NH * NL * DH * 4);
    float* klm  = (float*)alloc((size_t)NH * NL * DH * 4);
    float* wbuf = (float*)alloc((size_t)NH * NL * DH * 4);
    float* zwb  = (float*)alloc((size_t)NH * NL * DH * 4);
    float* a2   = (float*)alloc((size_t)NH * NL * NL * 4);
    float* zb0  = (float*)alloc((size_t)NH * NL * NL * 4);   // z0 (kept for final stage)
    float* zb1  = (float*)alloc((size_t)NH * NL * NL * 4);   // v ping-pong scratch
    float* azb  = (float*)alloc((size_t)NH * NL * NL * 4);   // w cur
    float* tb   = (float*)alloc((size_t)NH * NL * NL * 4);   // w next
    float* ub   = (float*)alloc((size_t)NH * NL * NL * 4);   // S = w@w
    float* Pbuf = (float*)alloc((size_t)6 * NH * NL * NL * 4);
    float* part = (float*)alloc(256);
    float* a3p  = (float*)alloc((size_t)NH * NL * 4 * 10 * 4);
    float* plan  = (float*)alloc((size_t)CCH * NPIX * 4);
    float* plan2 = (float*)alloc((size_t)CCH * NPIX * 4);
    float* wcomb = (float*)alloc((size_t)HD * 49 * 4);
    float* bsum  = (float*)alloc((size_t)HD * 4);
    short* wt1   = (short*)alloc((size_t)HD * ID * 2);
    short* wtq   = (short*)alloc((size_t)192 * HD * 2);
    short* xb    = (short*)alloc((size_t)NP * ID * 2);   // NP rows: fc1 A-tiles may read past NPIX
    short* xpB   = (short*)alloc((size_t)NP * HD * 2);
    (void)ws_size; (void)in_sizes; (void)n_in; (void)out_size;

    castX<<<(NPIX * ID / 8) / 256, 256, 0, stream>>>(x, xb);
    castT<<<dim3(HD / 32, ID / 32), 256, 0, stream>>>(fc1_w, wt1, ID, HD);
    gemm_fc1<<<dim3(154, 4), 256, 0, stream>>>(xb, wt1, fc1_b, bufA);
    cls_init<<<2, 256, 0, stream>>>(cls, bufA);

    auto attention = [&](float* hbuf, const float* lg, const float* lb,
                         const float* qkvw, const float* ow, const float* ob,
                         const float* rw) {
        ln_pad<<<NP, 256, 0, stream>>>(hbuf, lg, lb, xpB);
        castT<<<dim3(192 / 32, HD / 32), 256, 0, stream>>>(qkvw, wtq, HD, 192);
        gemm_qkv<<<dim3(NP / 64, 3), 256, 0, stream>>>(xpB, wtq, qh, kh, vh);
        landmarks<<<128, 256, 0, stream>>>(qh, kh, ql, klm);
        attn2_softmax<<<dim3(NL, NH), 256, 0, stream>>>(ql, klm, a2);
        pinv_norms<<<16, 256, 0, stream>>>(a2, part);
        z0_init<<<2048, 256, 0, stream>>>(a2, part, zb0);
        // w-space Newton-Schulz: w = a@z0; per iter S=w@w, P=13I-15w+7S-S@w,
        // w'=0.25*w@P.  z6 = 4^-6 * z0 @ P0 @ ... @ P5 recovered via polyv chain.
        mm256g<<<dim3(8, 4, 8), 256, 0, stream>>>(a2, zb0, azb, 1.f, 0.f, 0.f, 0.f);
        float* wc = azb;
        float* wn = tb;
        for (int it = 0; it < 6; ++it) {
            float* Ps = Pbuf + (size_t)it * NH * NL * NL;
            mm256g<<<dim3(8, 4, 8), 256, 0, stream>>>(wc, wc, ub, 1.f, 0.f, 0.f, 0.f);
            mm256g<<<dim3(8, 4, 8), 256, 0, stream>>>(ub, wc, Ps, -1.f, 7.f, -15.f, 13.f);
            if (it < 5) {
                mm256g<<<dim3(8, 4, 8), 256, 0, stream>>>(wc, Ps, wn, 0.25f, 0.f, 0.f, 0.f);
                float* tmp = wc; wc = wn; wn = tmp;
            }
        }
        attn3v<<<dim3(NL / 4, NH, 4), 256, 0, stream>>>(kh, vh, ql, a3p);
        attn3v_merge<<<8, 256, 0, stream>>>(a3p, wbuf);
        // zw = 4^-6 * z0 @ P0 @ ... @ P5 @ wbuf, right-to-left mat-vec chain
        {
            float* va  = zb1;
            float* vbb = zb1 + NH * NL * DH;
            const float* vcur = wbuf;
            for (int s = 5; s >= 0; --s) {
                float* vnext = ((5 - s) & 1) ? vbb : va;
                polyv<<<dim3(8, NH), 256, 0, stream>>>(Pbuf + (size_t)s * NH * NL * NL,
                                                       vcur, vnext, 1.f);
                vcur = vnext;
            }
            polyv<<<dim3(8, NH), 256, 0, stream>>>(zb0, vcur, zwb, 2.44140625e-4f);
        }
        attn1_conv<<<dim3(154, NH), 256, 0, stream>>>(qh, vh, klm, zwb, rw, aout);
        outproj<<<(NT + 15) / 16, 512, 0, stream>>>(aout, ow, ob, hbuf);
    };

    attention(bufA, l1_g, l1_bb, l1_qkv, l1_ow, l1_ob, l1_rw);

    ppeg_wprep<<<(HD * 49 + HD + 255) / 256, 256, 0, stream>>>(p7w, p7b, p5w, p5b, p3w, p3b,
                                                               wcomb, bsum);
    copy512<<<1, 512, 0, stream>>>(bufA, bufB);
    constexpr int PTILES = (NPIX + 31) / 32;
    for (int ch0 = 0; ch0 < HD; ch0 += CCH) {
        ppeg_t1<<<dim3(PTILES, CCH / 32), 256, 0, stream>>>(bufA, plan, ch0);
        ppeg_conv<<<dim3(CCH, 4), 256, 0, stream>>>(plan, wcomb, plan2, ch0);
        ppeg_t2<<<dim3(PTILES, CCH / 32), 256, 0, stream>>>(plan2, bsum, bufB, ch0);
    }

    attention(bufB, l2_g, l2_bb, l2_qkv, l2_ow, l2_ob, l2_rw);
    final_ln<<<1, 256, 0, stream>>>(bufB, ng, nb, out);
}